// Round 1
// 1259.502 us; speedup vs baseline: 1.0050x; 1.0050x over previous
//
#include <hip/hip_runtime.h>

#define ND 64
#define H1 128
#define H2 64

typedef float f4 __attribute__((ext_vector_type(4)));

// ---------------- K1: t1T[j, i] = tanh(x[i,:] @ W1[:,j] + b1[j]) ------------
// Block = 256 threads = 64 atoms x 4 j-chunks of 32. x tile staged in LDS
// (stride 65 -> 2-way bank aliasing = free). W1 wave-uniform. Output stored
// TRANSPOSED [H1, natoms] so downstream k-loops are lane-coalesced.
__global__ __launch_bounds__(256) void k1_h1(
    const float* __restrict__ x, const float* __restrict__ W1,
    const float* __restrict__ b1, float* __restrict__ t1T, int natoms)
{
    __shared__ float xs[64 * 65];
    const int t = threadIdx.x;
    const size_t xbase = (size_t)blockIdx.x * 64 * ND;
    const size_t xlimit = (size_t)natoms * ND;

    #pragma unroll
    for (int q = 0; q < 4; ++q) {
        int f = q * 1024 + t * 4;            // flat idx in 64x64 tile
        int atom = f >> 6, k = f & 63;
        float4 v = {0.f, 0.f, 0.f, 0.f};
        if (xbase + f < xlimit) v = *(const float4*)(x + xbase + f);
        xs[atom * 65 + k + 0] = v.x;
        xs[atom * 65 + k + 1] = v.y;
        xs[atom * 65 + k + 2] = v.z;
        xs[atom * 65 + k + 3] = v.w;
    }
    __syncthreads();

    const int atom = t & 63;                 // lane -> atom (coalesced)
    const int c = t >> 6;                    // wave -> j-chunk (uniform)
    const int i = blockIdx.x * 64 + atom;

    float acc[32];
    #pragma unroll
    for (int j = 0; j < 32; ++j) acc[j] = b1[c * 32 + j];
    for (int k = 0; k < ND; ++k) {
        float xk = xs[atom * 65 + k];
        const float* w = W1 + k * H1 + c * 32;
        #pragma unroll
        for (int j = 0; j < 32; ++j) acc[j] = fmaf(xk, w[j], acc[j]);
    }
    if (i < natoms) {
        #pragma unroll
        for (int j = 0; j < 32; ++j)
            t1T[(size_t)(c * 32 + j) * natoms + i] = tanhf(acc[j]);
    }
}

// ---------------- K2: fused h2 / energy / dz2 / dEdD ------------------------
// Thread-per-atom; all global reads lane-coalesced (t1T transposed).
// 64-thread blocks: 782 blocks -> all 256 CUs active (was 196 blocks of 256,
// leaving 60 CUs idle on a latency-bound kernel).
__global__ __launch_bounds__(64) void k2_rest(
    const float* __restrict__ t1T, const int* __restrict__ indices,
    const float* __restrict__ W1, const float* __restrict__ W2,
    const float* __restrict__ b2, const float* __restrict__ W3,
    const float* __restrict__ b3, float* __restrict__ energy,
    float* __restrict__ dEdD, int natoms)
{
    const int i = blockIdx.x * 64 + threadIdx.x;
    if (i >= natoms) return;

    // h2 = tanh(t1 @ W2 + b2)  — phase-1 t1T reads stay temporal (re-read in
    // phase 2 from L2).
    float h2[H2];
    #pragma unroll
    for (int j = 0; j < H2; ++j) h2[j] = b2[j];
    for (int k = 0; k < H1; ++k) {
        float hk = t1T[(size_t)k * natoms + i];
        const float* w = W2 + k * H2;
        #pragma unroll
        for (int j = 0; j < H2; ++j) h2[j] = fmaf(hk, w[j], h2[j]);
    }
    // e, dz2 = W3 * (1 - h2^2)
    float e = b3[0];
    float dz2[H2];
    #pragma unroll
    for (int j = 0; j < H2; ++j) {
        float v = tanhf(h2[j]);
        float w3 = W3[j];
        e = fmaf(v, w3, e);
        dz2[j] = w3 * (1.0f - v * v);
    }
    atomicAdd(&energy[indices[i]], e);

    // dEdD[k] = sum_j (1 - t1_j^2) * (dz2 . W2[j,:]) * W1[k,j]
    // phase-2 t1T reads are the LAST use -> nontemporal, don't displace the
    // dEdD lines we are about to write (pairs kernel gathers them next).
    float d[ND];
    #pragma unroll
    for (int k = 0; k < ND; ++k) d[k] = 0.0f;
    for (int j = 0; j < H1; ++j) {
        const float* w2r = W2 + j * H2;
        float dh1 = 0.0f;
        #pragma unroll
        for (int k = 0; k < H2; ++k) dh1 = fmaf(dz2[k], w2r[k], dh1);
        float tj = __builtin_nontemporal_load(t1T + (size_t)j * natoms + i);
        float dz1 = dh1 * (1.0f - tj * tj);
        const float* w1c = W1 + j;
        #pragma unroll
        for (int k = 0; k < ND; ++k) d[k] = fmaf(dz1, w1c[k * H1], d[k]);
    }
    float4* outp = (float4*)(dEdD + (size_t)i * ND);
    #pragma unroll
    for (int k = 0; k < ND; k += 4) {
        float4 v = {d[k], d[k + 1], d[k + 2], d[k + 3]};
        outp[k / 4] = v;
    }
}

// ---------------- fallback MLP (small ws): round-1 kernel -------------------
__global__ __launch_bounds__(128) void mlp_fallback(
    const float* __restrict__ x, const int* __restrict__ indices,
    const float* __restrict__ W1, const float* __restrict__ b1,
    const float* __restrict__ W2, const float* __restrict__ b2,
    const float* __restrict__ W3, const float* __restrict__ b3,
    float* __restrict__ energy, float* __restrict__ dEdD, int natoms)
{
    __shared__ float h1s[H1 * 128];
    const int t = threadIdx.x;
    const int i = blockIdx.x * 128 + t;
    if (i >= natoms) return;
    float h1[H1];
    #pragma unroll
    for (int j = 0; j < H1; ++j) h1[j] = b1[j];
    for (int k = 0; k < ND; ++k) {
        float xk = x[(size_t)i * ND + k];
        const float* w = W1 + k * H1;
        #pragma unroll
        for (int j = 0; j < H1; ++j) h1[j] = fmaf(xk, w[j], h1[j]);
    }
    #pragma unroll
    for (int j = 0; j < H1; ++j) h1s[j * 128 + t] = tanhf(h1[j]);
    float h2[H2];
    #pragma unroll
    for (int j = 0; j < H2; ++j) h2[j] = b2[j];
    for (int k = 0; k < H1; ++k) {
        float hk = h1s[k * 128 + t];
        const float* w = W2 + k * H2;
        #pragma unroll
        for (int j = 0; j < H2; ++j) h2[j] = fmaf(hk, w[j], h2[j]);
    }
    float e = b3[0];
    float dz2[H2];
    #pragma unroll
    for (int j = 0; j < H2; ++j) {
        float v = tanhf(h2[j]);
        float w3 = W3[j];
        e = fmaf(v, w3, e);
        dz2[j] = w3 * (1.0f - v * v);
    }
    atomicAdd(&energy[indices[i]], e);
    float d[ND];
    #pragma unroll
    for (int k = 0; k < ND; ++k) d[k] = 0.0f;
    for (int j = 0; j < H1; ++j) {
        const float* w2r = W2 + j * H2;
        float dh1 = 0.0f;
        #pragma unroll
        for (int k = 0; k < H2; ++k) dh1 = fmaf(dz2[k], w2r[k], dh1);
        float h = h1s[j * 128 + t];
        float dz1 = dh1 * (1.0f - h * h);
        const float* w1c = W1 + j;
        #pragma unroll
        for (int k = 0; k < ND; ++k) d[k] = fmaf(dz1, w1c[k * H1], d[k]);
    }
    float4* outp = (float4*)(dEdD + (size_t)i * ND);
    #pragma unroll
    for (int k = 0; k < ND; k += 4) {
        float4 v = {d[k], d[k + 1], d[k + 2], d[k + 3]};
        outp[k / 4] = v;
    }
}

// ---------------- pairs: 16 lanes per pair ----------------------------------
// Lane l of a 16-lane cluster loads float4 #l of each of the pair's 3 xd rows
// and of the gathered g row. xd / xd_indx / unique_j are used exactly once ->
// NONTEMPORAL loads so the 768 MB stream doesn't evict the 12.8 MB dEdD
// gather set from the 4 MB-per-XCD L2s. dEdD gather stays temporal (the only
// reused data here). Butterfly shfl_xor reduce; lanes 0/1/2 issue the atomics.
__global__ __launch_bounds__(256) void pairs16_kernel(
    const float* __restrict__ xd, const int* __restrict__ xd_indx,
    const int* __restrict__ unique_j, const float* __restrict__ dEdD,
    float* __restrict__ forces, int npairs)
{
    const size_t tid = (size_t)blockIdx.x * 256 + threadIdx.x;
    const int p = (int)(tid >> 4);
    const int sub = (int)(tid & 15);
    if (p >= npairs) return;

    const int neigh = __builtin_nontemporal_load(xd_indx + 6 * (size_t)p);
    const f4* g4 = (const f4*)(dEdD + (size_t)neigh * ND);
    const f4* a4 = (const f4*)(xd + (size_t)p * (3 * ND));

    f4 gv = g4[sub];                                    // temporal (reused set)
    f4 v0 = __builtin_nontemporal_load(a4 + sub);        // stream-once
    f4 v1 = __builtin_nontemporal_load(a4 + sub + 16);
    f4 v2 = __builtin_nontemporal_load(a4 + sub + 32);

    float sx = v0.x * gv.x + v0.y * gv.y + v0.z * gv.z + v0.w * gv.w;
    float sy = v1.x * gv.x + v1.y * gv.y + v1.z * gv.z + v1.w * gv.w;
    float sz = v2.x * gv.x + v2.y * gv.y + v2.z * gv.z + v2.w * gv.w;

    #pragma unroll
    for (int m = 8; m >= 1; m >>= 1) {
        sx += __shfl_xor(sx, m);
        sy += __shfl_xor(sy, m);
        sz += __shfl_xor(sz, m);
    }
    if (sub < 3) {
        float val = (sub == 0) ? sx : ((sub == 1) ? sy : sz);
        int uj = __builtin_nontemporal_load(unique_j + 3 * (size_t)p + sub);
        atomicAdd(&forces[3 * uj + sub], -val);
    }
}

extern "C" void kernel_launch(void* const* d_in, const int* in_sizes, int n_in,
                              void* d_out, int out_size, void* d_ws, size_t ws_size,
                              hipStream_t stream)
{
    const float* x        = (const float*)d_in[0];
    const float* xd       = (const float*)d_in[1];
    const int*   indices  = (const int*)d_in[2];
    const int*   xd_indx  = (const int*)d_in[4];
    const int*   unique_j = (const int*)d_in[5];
    const float* W1 = (const float*)d_in[6];
    const float* b1 = (const float*)d_in[7];
    const float* W2 = (const float*)d_in[8];
    const float* b2 = (const float*)d_in[9];
    const float* W3 = (const float*)d_in[10];
    const float* b3 = (const float*)d_in[11];

    const int natoms  = in_sizes[0] / ND;   // 50000
    const int nstruct = in_sizes[3];        // 250
    const int npairs  = in_sizes[5] / 3;    // 1e6

    float* out    = (float*)d_out;
    float* energy = out;
    float* forces = out + nstruct;

    float* dEdD = (float*)d_ws;                       // [natoms*64]  12.8 MB
    float* t1T  = (float*)d_ws + (size_t)natoms * ND; // [128*natoms] 25.6 MB

    const size_t need = (size_t)natoms * (ND + H1) * sizeof(float);

    hipMemsetAsync(d_out, 0, (size_t)out_size * sizeof(float), stream);

    if (ws_size >= need) {
        k1_h1<<<(natoms + 63) / 64, 256, 0, stream>>>(x, W1, b1, t1T, natoms);
        k2_rest<<<(natoms + 63) / 64, 64, 0, stream>>>(
            t1T, indices, W1, W2, b2, W3, b3, energy, dEdD, natoms);
    } else {
        mlp_fallback<<<(natoms + 127) / 128, 128, 0, stream>>>(
            x, indices, W1, b1, W2, b2, W3, b3, energy, dEdD, natoms);
    }

    pairs16_kernel<<<(npairs * 16 + 255) / 256, 256, 0, stream>>>(
        xd, xd_indx, unique_j, dEdD, forces, npairs);
}